// Round 9
// baseline (73.414 us; speedup 1.0000x reference)
//
#include <hip/hip_runtime.h>
#include <hip/hip_bf16.h>

// Problem constants (from setup_inputs): B=4, N=8192, M=8192, D=3, fp32.
constexpr int B = 4;
constexpr int N = 8192;
constexpr int M = 8192;

constexpr int QPW     = 64;            // queries per wave (2 B-fragments)
constexpr int WAVES   = 4;             // waves per block
constexpr int QB      = QPW * WAVES;   // 256 queries per block
constexpr int QTILES  = N / QB;        // 32
constexpr int PCHUNKS = 16;            // point split -> grid 2048 = 8 blocks/CU
constexpr int CHUNK   = M / PCHUNKS;   // 512 points per block
constexpr int PTILES  = CHUNK / 32;    // 16 A-tile reads, 32 mfmas per wave

typedef __bf16 bf16x8 __attribute__((ext_vector_type(8)));
typedef float  f32x16 __attribute__((ext_vector_type(16)));

union FragU { uint4 u; bf16x8 b; };

// fp32 -> bf16 bits, round-to-nearest-even (finite inputs only).
__device__ inline unsigned f2bf(float x) {
    unsigned u = __float_as_uint(x);
    return (u + 0x7FFFu + ((u >> 16) & 1u)) >> 16;
}
__device__ inline float bf2f(unsigned b) { return __uint_as_float(b << 16); }
__device__ inline unsigned pk(unsigned lo, unsigned hi) { return lo | (hi << 16); }

// ---------------------------------------------------------------------------
// K-slot packing (mfma_f32_32x32x16_bf16, A rows = points, B cols = queries):
//   k0..3 : A=(ph0,ph0,pl0,pl0)  B=(ah0,al0,ah0,al0)  -> (ph0+pl0)(ah0+al0)
//   k4..7 : dim 1   k8..11: dim 2   k12,13: A=(sh,sl) B=(1,1) -> ||p||^2
//   k14,15: 0         (p' = -2p, everything split bf16 hi/lo)
// acc[row=point][col=query] = -2 a.p + ||p||^2  (validated R7/R8: absmax
// 7.8e-3 vs 6.75e-2 threshold).
// A-frag layout: A[m=lane&31][k=(lane>>5)*8+j] -> two 16B halves per point,
// stored in LDS half-tables tile[h][p] (even bank spread: each wave-read is
// two contiguous 512B spans -> volume-bound, no conflict multiplier).
// ---------------------------------------------------------------------------

// Pack one point into its two A-fragment halves.
__device__ inline void pack_point(float p0, float p1, float p2,
                                  uint4& f0, uint4& f1) {
    const float v0 = -2.0f * p0, v1 = -2.0f * p1, v2 = -2.0f * p2;
    const unsigned h0 = f2bf(v0), l0 = f2bf(v0 - bf2f(h0));
    const unsigned h1 = f2bf(v1), l1 = f2bf(v1 - bf2f(h1));
    const unsigned h2 = f2bf(v2), l2 = f2bf(v2 - bf2f(h2));
    const float s = fmaf(p0, p0, fmaf(p1, p1, p2 * p2));
    const unsigned sh = f2bf(s), sl = f2bf(s - bf2f(sh));
    f0.x = pk(h0, h0); f0.y = pk(l0, l0); f0.z = pk(h1, h1); f0.w = pk(l1, l1); // k0..7
    f1.x = pk(h2, h2); f1.y = pk(l2, l2); f1.z = pk(sh, sl); f1.w = 0;          // k8..15
}

// Build the B fragment for query index q (this lane's column).
__device__ inline FragU make_bfrag(const float* __restrict__ input,
                                   int b, int q, int h, float& sq_a) {
    const float* a = input + ((size_t)b * N + q) * 3;
    const float a0 = a[0], a1 = a[1], a2 = a[2];
    sq_a = fmaf(a0, a0, fmaf(a1, a1, a2 * a2));
    const unsigned ah0 = f2bf(a0), al0 = f2bf(a0 - bf2f(ah0));
    const unsigned ah1 = f2bf(a1), al1 = f2bf(a1 - bf2f(ah1));
    const unsigned ah2 = f2bf(a2), al2 = f2bf(a2 - bf2f(ah2));
    FragU bq;
    const unsigned dA = h ? pk(ah2, al2) : pk(ah0, al0);
    const unsigned dB = h ? 0x3F803F80u  : pk(ah1, al1);   // (1,1) bf16 | dim1
    bq.u.x = dA;
    bq.u.y = dA;
    bq.u.z = dB;
    bq.u.w = h ? 0u : dB;
    return bq;
}

// Fused kernel: per block, pack own 512-point chunk into LDS (16 KB), then
// one wave = 64 queries (2 B frags) vs the chunk. Per 2 A-tile LDS reads:
// 4 mfmas + 16 v_min3. atomicMin(uint view) merges chunks (out pre-set to
// 0x7F7F7F7F; d2 >= 0 so uint order == float order).
__global__ __launch_bounds__(256, 3) void main_kernel(const float* __restrict__ input,
                                                      const float* __restrict__ point,
                                                      unsigned int* __restrict__ out) {
    const int bid    = blockIdx.x;
    const int pchunk = bid % PCHUNKS;
    const int qtile  = (bid / PCHUNKS) % QTILES;
    const int b      = bid / (PCHUNKS * QTILES);
    const int tid    = threadIdx.x;
    const int wave   = tid >> 6;
    const int lane   = tid & 63;
    const int col    = lane & 31;          // A: point row in tile; B: query col
    const int h      = lane >> 5;          // k-half

    __shared__ uint4 tile[2][CHUNK];       // 16 KB: [h][point]

    // --- stage + pack this block's point chunk (2 points per thread) ------
    {
        const float* pp = point + ((size_t)b * M + (size_t)pchunk * CHUNK) * 3;
        // floats 6*tid .. 6*tid+5 = points 2*tid, 2*tid+1 (8B-aligned pairs).
        const float2* pp2 = (const float2*)(pp + 6 * tid);
        const float2 u0 = pp2[0];
        const float2 u1 = pp2[1];
        const float2 u2 = pp2[2];
        uint4 f0, f1;
        pack_point(u0.x, u0.y, u1.x, f0, f1);
        tile[0][2 * tid + 0] = f0;
        tile[1][2 * tid + 0] = f1;
        pack_point(u1.y, u2.x, u2.y, f0, f1);
        tile[0][2 * tid + 1] = f0;
        tile[1][2 * tid + 1] = f1;
    }

    // --- B fragments (built while staging settles) ------------------------
    const int q0 = qtile * QB + wave * QPW + col;
    const int q1 = q0 + 32;
    float sq_a0, sq_a1;
    const FragU b0 = make_bfrag(input, b, q0, h, sq_a0);
    const FragU b1 = make_bfrag(input, b, q1, h, sq_a1);

    __syncthreads();

    const uint4* __restrict__ th = &tile[h][0];   // this lane's half-table

    f32x16 cz, rmin0, rmin1;
#pragma unroll
    for (int i = 0; i < 16; ++i) { cz[i] = 0.0f; rmin0[i] = 1e30f; rmin1[i] = 1e30f; }

    for (int t = 0; t < PTILES; t += 2) {
        FragU fa0, fa1;
        fa0.u = th[t * 32 + col];
        fa1.u = th[(t + 1) * 32 + col];
        f32x16 acc00 = __builtin_amdgcn_mfma_f32_32x32x16_bf16(fa0.b, b0.b, cz, 0, 0, 0);
        f32x16 acc01 = __builtin_amdgcn_mfma_f32_32x32x16_bf16(fa0.b, b1.b, cz, 0, 0, 0);
        f32x16 acc10 = __builtin_amdgcn_mfma_f32_32x32x16_bf16(fa1.b, b0.b, cz, 0, 0, 0);
        f32x16 acc11 = __builtin_amdgcn_mfma_f32_32x32x16_bf16(fa1.b, b1.b, cz, 0, 0, 0);
#pragma unroll
        for (int i = 0; i < 16; ++i) {
            rmin0[i] = fminf(rmin0[i], fminf(acc00[i], acc10[i]));   // v_min3_f32
            rmin1[i] = fminf(rmin1[i], fminf(acc01[i], acc11[i]));   // v_min3_f32
        }
    }

    // --- epilogue: in-lane fold + cross-half shuffle + atomic merge -------
    float m0 = rmin0[0], m1 = rmin1[0];
#pragma unroll
    for (int i = 1; i < 16; ++i) { m0 = fminf(m0, rmin0[i]); m1 = fminf(m1, rmin1[i]); }
    m0 = fminf(m0, __shfl_xor(m0, 32, 64));
    m1 = fminf(m1, __shfl_xor(m1, 32, 64));

    if (lane < 32) {
        atomicMin(&out[(size_t)b * N + q0], __float_as_uint(fmaxf(m0 + sq_a0, 0.0f)));
        atomicMin(&out[(size_t)b * N + q1], __float_as_uint(fmaxf(m1 + sq_a1, 0.0f)));
    }
}

extern "C" void kernel_launch(void* const* d_in, const int* in_sizes, int n_in,
                              void* d_out, int out_size, void* d_ws, size_t ws_size,
                              hipStream_t stream) {
    const float* input = (const float*)d_in[0];   // [B, N, 3] fp32
    const float* point = (const float*)d_in[1];   // [B, M, 3] fp32
    unsigned int* out  = (unsigned int*)d_out;    // [B, N] fp32 viewed as uint

    // Init output to 0x7F7F7F7F (3.39e38f): uint order == float order for
    // non-negative floats, so atomicMin(uint) implements float min.
    (void)hipMemsetAsync(d_out, 0x7F, (size_t)out_size * sizeof(float), stream);

    const int main_grid = B * QTILES * PCHUNKS;   // 2048 blocks
    main_kernel<<<main_grid, 256, 0, stream>>>(input, point, out);
}